// Round 12
// baseline (124.319 us; speedup 1.0000x reference)
//
#include <hip/hip_runtime.h>
#include <hip/hip_bf16.h>

// ConvSelfAttn: B=8, N=4096, C=64, d=8. FP32 I/O.
// R25: R24 + the R20 experiment EXECUTED PROPERLY. R20's V register
// double-buffer was silently undone by the compiler (VGPR 72 proved the
// prefetch loads were sunk back to their use). R25 pins the prefetch issue
// with a per-iteration asm volatile memory fence (loads cannot sink across
// a memory clobber): iter = {issue K/V loads for it+1 into named B buffers |
// FENCE | compute it from A buffers}, manual 2x unroll (static indexing).
// Entry loads hoisted before the Mkb reduce. Everything else = R24.
// Verification: VGPR ~110-140 (dbuf live). Tripwire: WRITE ~8.2MB (no spill).
// If attn >=50us with dbuf live -> latency-exposure theory dead, declare
// source-level ceiling next round.

#define BB 8
#define NN 4096
#define CC 64
#define PSTRIDE 72
#define LOG2E 1.44269504088896f

typedef _Float16 f16;
typedef _Float16 half8 __attribute__((ext_vector_type(8)));
typedef _Float16 half4 __attribute__((ext_vector_type(4)));
typedef __fp16 fp16x2 __attribute__((ext_vector_type(2)));
typedef float floatx4 __attribute__((ext_vector_type(4)));

static __device__ inline half4 pack4(float a, float b, float c, float d) {
    fp16x2 lo = __builtin_amdgcn_cvt_pkrtz(a, b);
    fp16x2 hi = __builtin_amdgcn_cvt_pkrtz(c, d);
    unsigned int lou = __builtin_bit_cast(unsigned int, lo);
    unsigned int hiu = __builtin_bit_cast(unsigned int, hi);
    unsigned long long packed = (unsigned long long)lou | ((unsigned long long)hiu << 32);
    return __builtin_bit_cast(half4, packed);
}

// ws layouts (halfs):
//   Qh [B*N][8]                          Q pre-scaled by log2e
//   Kf [B][128 pair][64 lane][8]         pair-interleaved QK A-frags; halfs
//                                        0-3 = even 16-key tile, 4-7 = odd;
//                                        quad2 = {1,0,0,0} (mf), quad3 = 0
//   Vf [B][128 pair][4 ct][64 lane][8]   16x16x16 PV A-frags; halfs 0-3 =
//                                        even 16-key tile (V[32p+4q+j][c]),
//                                        4-7 = odd tile (V[32p+16+4q+j][c])
//   qn2 [B*N] f32 | Mkb [512] f32 (per-proj-block key-norm max, no init)

// ---------------- fused projection + fragment repack + norms + key-max ----------------
// grid 512 x 256 (4 waves x 16 pixels; block = 64 pixels of one batch)
__global__ __launch_bounds__(256) void proj_all_kernel(
    const float* __restrict__ x,
    const float* __restrict__ wq, const float* __restrict__ bq,
    const float* __restrict__ wk, const float* __restrict__ bk,
    const float* __restrict__ wv, const float* __restrict__ bv,
    f16* __restrict__ Qh, f16* __restrict__ Kf, f16* __restrict__ Vf,
    float* __restrict__ qn2, float* __restrict__ Mkb)
{
    __shared__ alignas(16) f16 Ws[80][PSTRIDE];  // rows 0-63=V, 64-71=Q, 72-79=K
    __shared__ float Bs[80];
    __shared__ alignas(16) f16 Vst[64][68];      // TRANSPOSED: [ch][pixel], pitch 68
    __shared__ alignas(16) f16 Ks[64][12];       // [pixel][ch]
    __shared__ float redK[4];
    const int tid = threadIdx.x;

    // weight staging, float4-vectorized (wv: i = cin*64+cout)
    for (int i4 = tid; i4 < 1024; i4 += 256) {   // 4 iters
        const int i = i4 * 4;
        const int cin = i >> 6, cout = i & 63;   // 4 consecutive couts, same cin
        const float4 w = *(const float4*)(wv + i);
        Ws[cout + 0][cin] = (f16)w.x;
        Ws[cout + 1][cin] = (f16)w.y;
        Ws[cout + 2][cin] = (f16)w.z;
        Ws[cout + 3][cin] = (f16)w.w;
    }
    if (tid < 128) {                              // wq/wk: i = cin*8+c
        const int i = tid * 4;
        const int cin = i >> 3, c = i & 7;        // c in {0,4}
        const float4 a = *(const float4*)(wq + i);
        const float4 k = *(const float4*)(wk + i);
        Ws[64 + c + 0][cin] = (f16)(a.x * LOG2E);
        Ws[64 + c + 1][cin] = (f16)(a.y * LOG2E);
        Ws[64 + c + 2][cin] = (f16)(a.z * LOG2E);
        Ws[64 + c + 3][cin] = (f16)(a.w * LOG2E);
        Ws[72 + c + 0][cin] = (f16)k.x;
        Ws[72 + c + 1][cin] = (f16)k.y;
        Ws[72 + c + 2][cin] = (f16)k.z;
        Ws[72 + c + 3][cin] = (f16)k.w;
    }
    if (tid < 80)
        Bs[tid] = (tid < 64) ? bv[tid]
                : (tid < 72 ? bq[tid - 64] * LOG2E : bk[tid - 72]);
    __syncthreads();

    const int wave = tid >> 6, lane = tid & 63;
    const int quad = lane >> 4, n16 = lane & 15;
    const long pb = (long)blockIdx.x * 64;
    const long p0 = pb + wave * 16;
    const int  b   = (int)(pb >> 12);
    const int  nnb = (int)(pb & 4095);

    half8 ax[2];
#pragma unroll
    for (int kh = 0; kh < 2; ++kh) {
        const float* xp = x + (p0 + n16) * 64 + kh * 32 + quad * 8;
        float4 x1 = *(const float4*)xp;
        float4 x2 = *(const float4*)(xp + 4);
        ax[kh][0] = (f16)x1.x; ax[kh][1] = (f16)x1.y;
        ax[kh][2] = (f16)x1.z; ax[kh][3] = (f16)x1.w;
        ax[kh][4] = (f16)x2.x; ax[kh][5] = (f16)x2.y;
        ax[kh][6] = (f16)x2.z; ax[kh][7] = (f16)x2.w;
    }

#pragma unroll
    for (int ct = 0; ct < 5; ++ct) {
        const int cout = (ct < 4) ? ct * 16 + n16 : 64 + n16;
        const float bias = Bs[cout];
        half8 b0 = *(const half8*)(&Ws[cout][quad * 8]);
        half8 b1 = *(const half8*)(&Ws[cout][32 + quad * 8]);
        floatx4 acc = {bias, bias, bias, bias};
        acc = __builtin_amdgcn_mfma_f32_16x16x32_f16(ax[0], b0, acc, 0, 0, 0);
        acc = __builtin_amdgcn_mfma_f32_16x16x32_f16(ax[1], b1, acc, 0, 0, 0);
        if (ct < 4) {
            // transposed store: one half4 of 4 consecutive pixels
            half4 vp = {(f16)acc[0], (f16)acc[1], (f16)acc[2], (f16)acc[3]};
            *(half4*)(&Vst[ct * 16 + n16][wave * 16 + quad * 4]) = vp;
        } else {
            float n2[4];
#pragma unroll
            for (int r = 0; r < 4; ++r) n2[r] = acc[r] * acc[r];
#pragma unroll
            for (int d = 1; d < 8; d <<= 1)
#pragma unroll
                for (int r = 0; r < 4; ++r) n2[r] += __shfl_xor(n2[r], d, 64);
            if (n16 == 0) {
#pragma unroll
                for (int r = 0; r < 4; ++r) qn2[p0 + quad * 4 + r] = n2[r];
            }
            // fused per-batch key max: lanes n16>=8 hold kn2 sums
            float km = fmaxf(fmaxf(n2[0], n2[1]), fmaxf(n2[2], n2[3]));
            km = fmaxf(km, __shfl_xor(km, 16, 64));
            km = fmaxf(km, __shfl_xor(km, 32, 64));
            if (n16 == 8) redK[wave] = km;
            if (n16 < 8) {
                f16* dst = Qh + (p0 + quad * 4) * 8 + n16;
#pragma unroll
                for (int r = 0; r < 4; ++r) dst[r * 8] = (f16)acc[r];
            } else {
#pragma unroll
                for (int r = 0; r < 4; ++r)
                    Ks[wave * 16 + quad * 4 + r][n16 - 8] = (f16)acc[r];
            }
        }
    }
    __syncthreads();

    // per-block key-max slot (plain store — no init dispatch needed)
    if (tid == 0) {
        float m = fmaxf(fmaxf(redK[0], redK[1]), fmaxf(redK[2], redK[3]));
        Mkb[blockIdx.x] = m;
    }

    // V fragment stores (2 tiles per wave): gather = two half4 reads from Vst
#pragma unroll
    for (int u = 0; u < 2; ++u) {
        const int tt = wave * 2 + u;
        const int kb = tt >> 2, ct = tt & 3;
        half4 lo = *(const half4*)(&Vst[ct * 16 + n16][kb * 32 + quad * 4]);
        half4 hi = *(const half4*)(&Vst[ct * 16 + n16][kb * 32 + 16 + quad * 4]);
        half8 v = {lo[0], lo[1], lo[2], lo[3], hi[0], hi[1], hi[2], hi[3]};
        const size_t kbg = (size_t)b * 128 + (nnb >> 5) + kb;
        *(half8*)(Vf + (kbg * 4 + ct) * 512 + lane * 8) = v;
    }
    // K pair-tile stores: waves 0-1 each store one pair as full 16B/lane lines
    if (wave < 2) {
        half8 kp = {0, 0, 0, 0, 0, 0, 0, 0};
#pragma unroll
        for (int e = 0; e < 2; ++e) {
            const int t = wave * 2 + e;
            if (quad < 2) {
                half4 kd = *(const half4*)(&Ks[t * 16 + n16][quad * 4]);
                kp[e * 4 + 0] = kd[0]; kp[e * 4 + 1] = kd[1];
                kp[e * 4 + 2] = kd[2]; kp[e * 4 + 3] = kd[3];
            } else if (quad == 2) {
                kp[e * 4 + 0] = (f16)1.f;  // mf ones channel
            }
        }
        const size_t kpg = (size_t)b * 128 + (nnb >> 5) + wave;
        *(half8*)(Kf + kpg * 512 + lane * 8) = kp;
    }
}

// ---------------- flash attention, static-max, 32 q/wave, key-split 4 ----------------
// R16 compute body; K/V register double-buffer with fence-pinned 1-iter
// prefetch. grid B*128 = 1024 x 256 thr; wave = ks (0..3): keys
// [ks*1024,+1024), 16 iters of 64 keys. P never touches LDS.
__global__ __launch_bounds__(256, 3) void attn_kernel(
    const f16* __restrict__ Qh, const f16* __restrict__ Kf,
    const f16* __restrict__ Vf,
    const float* __restrict__ qn2, const float* __restrict__ Mkb,
    const float* __restrict__ x, const float* __restrict__ gptr,
    float* __restrict__ out)
{
    // smem: Obuf only (f32, stride 20, 3 partial ks x 2 qt2 x 64 lanes x 16ch)
    __shared__ alignas(16) char smem[30720];
    __shared__ float Ls[4][2][16];
    float* Obuf = (float*)smem;

    const int tid  = threadIdx.x;
    const int wave = tid >> 6, lane = tid & 63;
    const int quad = lane >> 4, n16 = lane & 15;
    const int ks = wave;

    const int b  = blockIdx.x & 7;
    const int qt = blockIdx.x >> 3;               // 0..127 (32-query tile)
    const size_t bN = (size_t)b * NN;

    const f16* kfb = Kf + ((size_t)b * 128 + ks * 32) * 512 + lane * 8;
    const f16* vfb = Vf + ((size_t)b * 128 + ks * 32) * 2048 + lane * 8;
    const floatx4 zero4 = {0.f, 0.f, 0.f, 0.f};

    // ---- issue all entry loads BEFORE the Mkb reduce (independent) ----
    half8 kkA0 = *(const half8*)(kfb + 0);
    half8 kkA1 = *(const half8*)(kfb + 512);
    half8 avA[2][4], avB[2][4];
    half8 kkB0, kkB1;
#pragma unroll
    for (int p = 0; p < 2; ++p)
#pragma unroll
        for (int ct = 0; ct < 4; ++ct)
            avA[p][ct] = *(const half8*)(vfb + ((size_t)p * 4 + ct) * 512);

    float q2v[2];
    half4 qv[2];
#pragma unroll
    for (int qt2 = 0; qt2 < 2; ++qt2) {
        const int q = qt * 32 + qt2 * 16 + n16;
        q2v[qt2] = qn2[bN + q];
        half4 v = {0, 0, 0, 0};
        if (quad < 2)
            v = *(const half4*)(Qh + (bN + q) * 8 + quad * 4);
        qv[qt2] = v;
    }

    // per-batch key-norm max: reduce this batch's 64 per-proj-block slots
    float mk2;
    {
        float m = Mkb[b * 64 + lane];             // lanes 0..63 cover all slots
        m = fmaxf(m, __shfl_xor(m, 1, 64));
        m = fmaxf(m, __shfl_xor(m, 2, 64));
        m = fmaxf(m, __shfl_xor(m, 4, 64));
        m = fmaxf(m, __shfl_xor(m, 8, 64));
        m = fmaxf(m, __shfl_xor(m, 16, 64));
        m = fmaxf(m, __shfl_xor(m, 32, 64));
        mk2 = m;
    }

    // Q B-frags: quads 0-1 = Q data; quad2 = {-mf,0,0,0}; quad3 = 0.
    half4 bq4[2];
#pragma unroll
    for (int qt2 = 0; qt2 < 2; ++qt2) {
        const float mf = __builtin_sqrtf(q2v[qt2] * mk2) - 12.0f;
        half4 v = qv[qt2];
        if (quad == 2)
            v[0] = (f16)(-mf);
        bq4[qt2] = v;
    }

    floatx4 oacc[2][4];
#pragma unroll
    for (int qt2 = 0; qt2 < 2; ++qt2)
#pragma unroll
        for (int ct = 0; ct < 4; ++ct) oacc[qt2][ct] = (floatx4){0.f, 0.f, 0.f, 0.f};
    float l_loc[2] = {0.f, 0.f};

    // iter: prefetch it+1 into (nk,nav), FENCE (pins issue — loads cannot
    // sink across a memory clobber), then compute it from (ck,cav).
    auto iter = [&](int it, half8& ck0, half8& ck1, half8 (&cav)[2][4],
                    half8& nk0, half8& nk1, half8 (&nav)[2][4]) {
        const int itn = (it < 15) ? it + 1 : 15;
        nk0 = *(const half8*)(kfb + (size_t)itn * 1024);
        nk1 = *(const half8*)(kfb + (size_t)itn * 1024 + 512);
#pragma unroll
        for (int p = 0; p < 2; ++p)
#pragma unroll
            for (int ct = 0; ct < 4; ++ct)
                nav[p][ct] = *(const half8*)(vfb + ((size_t)(itn * 2 + p) * 4 + ct) * 512);
        __asm__ volatile("" ::: "memory");     // pin prefetch issue here

        half4 ak[4];
        ak[0] = __builtin_shufflevector(ck0, ck0, 0, 1, 2, 3);
        ak[1] = __builtin_shufflevector(ck0, ck0, 4, 5, 6, 7);
        ak[2] = __builtin_shufflevector(ck1, ck1, 0, 1, 2, 3);
        ak[3] = __builtin_shufflevector(ck1, ck1, 4, 5, 6, 7);

#pragma unroll
        for (int qt2 = 0; qt2 < 2; ++qt2) {
            floatx4 sf[4];
#pragma unroll
            for (int t = 0; t < 4; ++t)
                sf[t] = __builtin_amdgcn_mfma_f32_16x16x16f16(ak[t], bq4[qt2], zero4, 0, 0, 0);

            half4 pk[4];
            float rst[4];
#pragma unroll
            for (int t = 0; t < 4; ++t) {
                float p0 = __builtin_exp2f(sf[t][0]);
                float p1 = __builtin_exp2f(sf[t][1]);
                float p2 = __builtin_exp2f(sf[t][2]);
                float p3 = __builtin_exp2f(sf[t][3]);
                rst[t] = (p0 + p1) + (p2 + p3);
                pk[t] = pack4(p0, p1, p2, p3);
            }
            l_loc[qt2] += (rst[0] + rst[1]) + (rst[2] + rst[3]);

            // PV: 16x16x16, A = V tile frag (even/odd half of pair), B = pk[t]
#pragma unroll
            for (int t = 0; t < 4; ++t) {
                const int p = t >> 1;
#pragma unroll
                for (int ct = 0; ct < 4; ++ct) {
                    half4 va = (t & 1)
                        ? __builtin_shufflevector(cav[p][ct], cav[p][ct], 4, 5, 6, 7)
                        : __builtin_shufflevector(cav[p][ct], cav[p][ct], 0, 1, 2, 3);
                    oacc[qt2][ct] = __builtin_amdgcn_mfma_f32_16x16x16f16(va, pk[t], oacc[qt2][ct], 0, 0, 0);
                }
            }
        }
    };

    for (int i2 = 0; i2 < 8; ++i2) {
        iter(i2 * 2,     kkA0, kkA1, avA, kkB0, kkB1, avB);
        iter(i2 * 2 + 1, kkB0, kkB1, avB, kkA0, kkA1, avA);
    }

    float l_run[2];
#pragma unroll
    for (int qt2 = 0; qt2 < 2; ++qt2) {
        float l = l_loc[qt2];
        l += __shfl_xor(l, 16, 64);
        l += __shfl_xor(l, 32, 64);
        l_run[qt2] = l;
    }

    __syncthreads();   // Obuf combine (f32, stride 20)
    if (ks > 0) {
#pragma unroll
        for (int qt2 = 0; qt2 < 2; ++qt2) {
            if (quad == 0) Ls[ks][qt2][n16] = l_run[qt2];
            float* ob = Obuf + (size_t)(((ks - 1) * 2 + qt2) * 64 + lane) * 20;
#pragma unroll
            for (int ct = 0; ct < 4; ++ct)
                *(floatx4*)(ob + ct * 4) = oacc[qt2][ct];
        }
    }
    __syncthreads();
    if (ks == 0) {
        const float g = gptr[0];
#pragma unroll
        for (int qt2 = 0; qt2 < 2; ++qt2) {
            float l = l_run[qt2];
            float o[16];
#pragma unroll
            for (int ct = 0; ct < 4; ++ct)
#pragma unroll
                for (int r = 0; r < 4; ++r) o[ct * 4 + r] = oacc[qt2][ct][r];
#pragma unroll
            for (int p = 1; p < 4; ++p) {
                l += Ls[p][qt2][n16];
                const float* ob = Obuf + (size_t)(((p - 1) * 2 + qt2) * 64 + lane) * 20;
#pragma unroll
                for (int ct = 0; ct < 4; ++ct) {
                    floatx4 t = *(const floatx4*)(ob + ct * 4);
                    o[ct * 4 + 0] += t[0]; o[ct * 4 + 1] += t[1];
                    o[ct * 4 + 2] += t[2]; o[ct * 4 + 3] += t[3];
                }
            }
            const float scale = g / l;
            const int q = qt * 32 + qt2 * 16 + n16;
#pragma unroll
            for (int ct = 0; ct < 4; ++ct) {
                const size_t idx = (bN + q) * CC + ct * 16 + quad * 4;
                float4 xr = *(const float4*)(x + idx);
                float4 res;
                res.x = o[ct * 4 + 0] * scale + xr.x;
                res.y = o[ct * 4 + 1] * scale + xr.y;
                res.z = o[ct * 4 + 2] * scale + xr.z;
                res.w = o[ct * 4 + 3] * scale + xr.w;
                *(float4*)(out + idx) = res;
            }
        }
    }
}

extern "C" void kernel_launch(void* const* d_in, const int* in_sizes, int n_in,
                              void* d_out, int out_size, void* d_ws, size_t ws_size,
                              hipStream_t stream) {
    const float* x     = (const float*)d_in[0];
    const float* wq    = (const float*)d_in[1];
    const float* bq    = (const float*)d_in[2];
    const float* wk    = (const float*)d_in[3];
    const float* bk    = (const float*)d_in[4];
    const float* wv    = (const float*)d_in[5];
    const float* bv    = (const float*)d_in[6];
    const float* gamma = (const float*)d_in[7];
    float* out = (float*)d_out;

    // ws: Qh 512KB | Kf 1MB | Vf 4MB | qn2 128KB | Mkb 2KB (per-block maxima)
    f16* Qh = (f16*)d_ws;
    f16* Kf = Qh + (size_t)BB * NN * 8;
    f16* Vf = Kf + (size_t)BB * 128 * 512;
    float* qn2 = (float*)(Vf + (size_t)BB * 128 * 4 * 512);
    float* Mkb = qn2 + (size_t)BB * NN;

    proj_all_kernel<<<512, 256, 0, stream>>>(x, wq, bq, wk, bk, wv, bv,
                                             Qh, Kf, Vf, qn2, Mkb);
    attn_kernel<<<BB * 128, 256, 0, stream>>>(Qh, Kf, Vf, qn2, Mkb, x, gamma, out);
}